// Round 1
// baseline (157.965 us; speedup 1.0000x reference)
//
#include <hip/hip_runtime.h>
#include <math.h>

#define KNN 5
#define GROUP 16                      // threads cooperating on one source point
#define BLOCK 256
#define SRC_PER_BLOCK (BLOCK / GROUP) // 16 source points per block
#define TILE_T 2048                   // target points per LDS tile
#define TILE_F (TILE_T * 3)           // floats per tile (24 KB)

// ---------------- small utility kernels ----------------

__global__ void init_acc_kernel(float* acc) {
    acc[0] = 0.0f;  // sum of knn distances (masked by valid source)
    acc[1] = 0.0f;  // count of valid source points
}

// Replace invalid (all-zero) target points with a far-away sentinel so the
// hot loop needs no validity check. Sentinel distance ~1e10 only ever enters
// the top-5 if there are <5 valid targets (impossible for this input).
__global__ void sanitize_targets_kernel(const float* __restrict__ tgt,
                                        float* __restrict__ out, int nt) {
    int i = blockIdx.x * blockDim.x + threadIdx.x;
    if (i >= nt) return;
    float x = tgt[3 * i + 0];
    float y = tgt[3 * i + 1];
    float z = tgt[3 * i + 2];
    bool valid = (x != 0.0f) || (y != 0.0f) || (z != 0.0f);
    if (!valid) { x = 1e10f; y = 0.0f; z = 0.0f; }
    out[3 * i + 0] = x;
    out[3 * i + 1] = y;
    out[3 * i + 2] = z;
}

__global__ void finalize_kernel(const float* acc, float* out) {
    out[0] = acc[0] / (acc[1] * (float)KNN);
}

// ---------------- main knn kernel ----------------

// Branch-guarded insert of squared distance v into ascending list k0..k4.
#define INSERT5(v)                                                        \
    do {                                                                  \
        float _v = (v);                                                   \
        if (_v < k4) {                                                    \
            float _t;                                                     \
            k4 = _v;                                                      \
            _t = fminf(k3, k4); k4 = fmaxf(k3, k4); k3 = _t;              \
            _t = fminf(k2, k3); k3 = fmaxf(k2, k3); k2 = _t;              \
            _t = fminf(k1, k2); k2 = fmaxf(k1, k2); k1 = _t;              \
            _t = fminf(k0, k1); k1 = fmaxf(k0, k1); k0 = _t;              \
        }                                                                 \
    } while (0)

template <bool CHECK_TGT_VALID>
__global__ __launch_bounds__(BLOCK) void knn_main_kernel(
        const float* __restrict__ src, const float* __restrict__ tgt,
        float* acc, int ms, int nt) {
    __shared__ float lds[TILE_F];
    __shared__ float red_sum[SRC_PER_BLOCK];
    __shared__ float red_cnt[SRC_PER_BLOCK];

    const int tid = threadIdx.x;
    const int g = tid / GROUP;   // which source point in this block
    const int m = tid % GROUP;   // member within the group
    const int sp = blockIdx.x * SRC_PER_BLOCK + g;

    float sx = 0.0f, sy = 0.0f, sz = 0.0f;
    bool sval = false;
    if (sp < ms) {
        sx = src[3 * sp + 0];
        sy = src[3 * sp + 1];
        sz = src[3 * sp + 2];
        sval = (sx != 0.0f) || (sy != 0.0f) || (sz != 0.0f);
    }

    // top-5 smallest squared distances, ascending
    float k0 = 1e30f, k1 = 1e30f, k2 = 1e30f, k3 = 1e30f, k4 = 1e30f;

    for (int t0 = 0; t0 < nt; t0 += TILE_T) {
        const int cnt = min(TILE_T, nt - t0);
        const int nf = cnt * 3;
        const long base = (long)t0 * 3;

        // stage tile into LDS (float4 when possible)
        if ((nf & 3) == 0) {
            for (int f = tid * 4; f < nf; f += BLOCK * 4) {
                float4 v = *reinterpret_cast<const float4*>(&tgt[base + f]);
                *reinterpret_cast<float4*>(&lds[f]) = v;
            }
        } else {
            for (int f = tid; f < nf; f += BLOCK) lds[f] = tgt[base + f];
        }
        __syncthreads();

        const float* lp = lds + 3 * m;
        const int iters = (cnt - m + GROUP - 1) / GROUP;  // targets this member scans
        #pragma unroll 4
        for (int i = 0; i < iters; ++i) {
            float x = lp[0], y = lp[1], z = lp[2];
            lp += 3 * GROUP;
            float dx = x - sx, dy = y - sy, dz = z - sz;
            float d2 = dx * dx + dy * dy + dz * dz;
            if (CHECK_TGT_VALID) {
                bool tv = (x != 0.0f) || (y != 0.0f) || (z != 0.0f);
                d2 = tv ? d2 : 1e20f;
            }
            INSERT5(d2);
        }
        __syncthreads();
    }

    // butterfly merge across the 16 members (offsets 8,4,2,1 stay in-group)
    for (int off = GROUP / 2; off >= 1; off >>= 1) {
        float p0 = __shfl_xor(k0, off);
        float p1 = __shfl_xor(k1, off);
        float p2 = __shfl_xor(k2, off);
        float p3 = __shfl_xor(k3, off);
        float p4 = __shfl_xor(k4, off);
        INSERT5(p0);
        INSERT5(p1);
        INSERT5(p2);
        INSERT5(p3);
        INSERT5(p4);
    }

    // member 0 of each group reports (sum of 5 sqrt distances, valid flag)
    if (m == 0) {
        float s5 = 0.0f;
        float c = 0.0f;
        if (sp < ms && sval) {
            s5 = sqrtf(fmaxf(k0, 1e-12f)) + sqrtf(fmaxf(k1, 1e-12f)) +
                 sqrtf(fmaxf(k2, 1e-12f)) + sqrtf(fmaxf(k3, 1e-12f)) +
                 sqrtf(fmaxf(k4, 1e-12f));
            c = 1.0f;
        }
        red_sum[g] = s5;
        red_cnt[g] = c;
    }
    __syncthreads();

    if (tid == 0) {
        float s = 0.0f, c = 0.0f;
        #pragma unroll
        for (int i = 0; i < SRC_PER_BLOCK; ++i) {
            s += red_sum[i];
            c += red_cnt[i];
        }
        atomicAdd(&acc[0], s);
        atomicAdd(&acc[1], c);
    }
}

// ---------------- launch ----------------

extern "C" void kernel_launch(void* const* d_in, const int* in_sizes, int n_in,
                              void* d_out, int out_size, void* d_ws, size_t ws_size,
                              hipStream_t stream) {
    const float* src = (const float*)d_in[0];
    const float* tgt = (const float*)d_in[1];
    const int ms = in_sizes[0] / 3;
    const int nt = in_sizes[1] / 3;

    float* acc = (float*)d_ws;  // 2 floats of accumulators at ws start
    init_acc_kernel<<<1, 1, 0, stream>>>(acc);

    const int blocks = (ms + SRC_PER_BLOCK - 1) / SRC_PER_BLOCK;
    const size_t need = 16 + (size_t)nt * 3 * sizeof(float);

    if (ws_size >= need) {
        float* st = (float*)((char*)d_ws + 16);
        sanitize_targets_kernel<<<(nt + 255) / 256, 256, 0, stream>>>(tgt, st, nt);
        knn_main_kernel<false><<<blocks, BLOCK, 0, stream>>>(src, st, acc, ms, nt);
    } else {
        knn_main_kernel<true><<<blocks, BLOCK, 0, stream>>>(src, tgt, acc, ms, nt);
    }

    finalize_kernel<<<1, 1, 0, stream>>>(acc, (float*)d_out);
}

// Round 2
// 107.140 us; speedup vs baseline: 1.4744x; 1.4744x over previous
//
#include <hip/hip_runtime.h>
#include <math.h>

#define KNN 5
#define BLOCK 256
#define TILE_T 2048                    // targets per LDS tile (SoA, 32 KB)
#define WAVES_PER_BLOCK (BLOCK / 64)   // 4
#define SRC_PER_WAVE 4                 // source points owned by each wave
#define SRC_PER_BLOCK (WAVES_PER_BLOCK * SRC_PER_WAVE)  // 16

// ---------------- small utility kernels ----------------

__global__ void init_acc_kernel(float* acc) {
    acc[0] = 0.0f;  // sum of knn distances over valid sources
    acc[1] = 0.0f;  // count of valid sources
}

__global__ void finalize_kernel(const float* acc, float* out) {
    out[0] = acc[0] / (acc[1] * (float)KNN);
}

// Branchless online top-5 (ascending k0..k4), 9 min/max, no exec-mask churn.
#define INS5(K0, K1, K2, K3, K4, V)                                       \
    do {                                                                  \
        float _v = (V);                                                   \
        K4 = fminf(K4, fmaxf(K3, _v));                                    \
        K3 = fminf(K3, fmaxf(K2, _v));                                    \
        K2 = fminf(K2, fmaxf(K1, _v));                                    \
        K1 = fminf(K1, fmaxf(K0, _v));                                    \
        K0 = fminf(K0, _v);                                               \
    } while (0)

// ---------------- main kernel ----------------
// One wave owns 4 source points; all 64 lanes scan disjoint 4-target chunks
// of each LDS tile, maintaining 4 branchless top-5 lists on q = t2 - 2*s.t
// (monotone in d^2; s2 added after selection). Lane-lists merged at the end
// with a 25-op lowest-5-of-two-sorted-5 network per butterfly round.

__global__ __launch_bounds__(BLOCK) void knn_kernel(
        const float* __restrict__ src, const float* __restrict__ tgt,
        float* __restrict__ acc, int ms, int nt) {
    __shared__ __align__(16) float xs[TILE_T];
    __shared__ __align__(16) float ys[TILE_T];
    __shared__ __align__(16) float zs[TILE_T];
    __shared__ __align__(16) float w2[TILE_T];  // |t|^2 (or sentinel)
    __shared__ float red_s[WAVES_PER_BLOCK];
    __shared__ float red_c[WAVES_PER_BLOCK];

    const int tid = threadIdx.x;
    const int wv = tid >> 6;
    const int lane = tid & 63;
    const int sbase = (blockIdx.x * WAVES_PER_BLOCK + wv) * SRC_PER_WAVE;

    // source points for this wave: precompute -2*s and |s|^2
    float nx[SRC_PER_WAVE], ny[SRC_PER_WAVE], nz[SRC_PER_WAVE];
    float s2a[SRC_PER_WAVE], svalid[SRC_PER_WAVE];
#pragma unroll
    for (int s = 0; s < SRC_PER_WAVE; ++s) {
        int sp = sbase + s;
        float x = 0.0f, y = 0.0f, z = 0.0f;
        if (sp < ms) {
            x = src[3 * sp + 0];
            y = src[3 * sp + 1];
            z = src[3 * sp + 2];
        }
        svalid[s] = (sp < ms && (x != 0.0f || y != 0.0f || z != 0.0f)) ? 1.0f : 0.0f;
        nx[s] = -2.0f * x;
        ny[s] = -2.0f * y;
        nz[s] = -2.0f * z;
        s2a[s] = fmaf(x, x, fmaf(y, y, z * z));
    }

    // 4 ascending top-5 lists (on q); fully register-resident (static idx only)
    float q0[SRC_PER_WAVE], q1[SRC_PER_WAVE], q2[SRC_PER_WAVE],
          q3[SRC_PER_WAVE], q4[SRC_PER_WAVE];
#pragma unroll
    for (int s = 0; s < SRC_PER_WAVE; ++s) {
        q0[s] = 1e30f; q1[s] = 1e30f; q2[s] = 1e30f; q3[s] = 1e30f; q4[s] = 1e30f;
    }

    for (int t0 = 0; t0 < nt; t0 += TILE_T) {
        // ---- stage tile into SoA LDS, sanitizing invalid targets ----
        if (t0 + TILE_T <= nt) {
            // full tile: vectorized, 3 float4 loads unpack to 4 targets
            const float4* t4 = reinterpret_cast<const float4*>(tgt + (size_t)t0 * 3);
#pragma unroll
            for (int cc = 0; cc < TILE_T / 4; cc += BLOCK) {
                int c = cc + tid;  // 4-target chunk within tile
                float4 f0 = t4[3 * c + 0];
                float4 f1 = t4[3 * c + 1];
                float4 f2 = t4[3 * c + 2];
                float px[4] = {f0.x, f0.w, f1.z, f2.y};
                float py[4] = {f0.y, f1.x, f1.w, f2.z};
                float pz[4] = {f0.z, f1.y, f2.x, f2.w};
                float pw[4];
#pragma unroll
                for (int j = 0; j < 4; ++j) {
                    bool v = (px[j] != 0.0f) || (py[j] != 0.0f) || (pz[j] != 0.0f);
                    if (!v) { px[j] = 1e10f; py[j] = 0.0f; pz[j] = 0.0f; }
                    pw[j] = fmaf(px[j], px[j], fmaf(py[j], py[j], pz[j] * pz[j]));
                }
                int t = 4 * c;
                *reinterpret_cast<float4*>(&xs[t]) = make_float4(px[0], px[1], px[2], px[3]);
                *reinterpret_cast<float4*>(&ys[t]) = make_float4(py[0], py[1], py[2], py[3]);
                *reinterpret_cast<float4*>(&zs[t]) = make_float4(pz[0], pz[1], pz[2], pz[3]);
                *reinterpret_cast<float4*>(&w2[t]) = make_float4(pw[0], pw[1], pw[2], pw[3]);
            }
        } else {
            // partial tail tile: scalar guarded + sentinel padding
            int cnt = nt - t0;
            for (int t = tid; t < TILE_T; t += BLOCK) {
                float x = 1e10f, y = 0.0f, z = 0.0f;
                if (t < cnt) {
                    x = tgt[3 * (size_t)(t0 + t) + 0];
                    y = tgt[3 * (size_t)(t0 + t) + 1];
                    z = tgt[3 * (size_t)(t0 + t) + 2];
                    if (x == 0.0f && y == 0.0f && z == 0.0f) { x = 1e10f; y = 0.0f; z = 0.0f; }
                }
                xs[t] = x; ys[t] = y; zs[t] = z;
                w2[t] = fmaf(x, x, fmaf(y, y, z * z));
            }
        }
        __syncthreads();

        // ---- scan tile: each lane takes 4 consecutive targets per iter ----
#pragma unroll 2
        for (int i = 0; i < TILE_T / 256; ++i) {
            int t = (i << 8) + (lane << 2);
            float4 x4 = *reinterpret_cast<const float4*>(&xs[t]);
            float4 y4 = *reinterpret_cast<const float4*>(&ys[t]);
            float4 z4 = *reinterpret_cast<const float4*>(&zs[t]);
            float4 w4 = *reinterpret_cast<const float4*>(&w2[t]);
#pragma unroll
            for (int s = 0; s < SRC_PER_WAVE; ++s) {
                float qa = fmaf(nx[s], x4.x, fmaf(ny[s], y4.x, fmaf(nz[s], z4.x, w4.x)));
                float qb = fmaf(nx[s], x4.y, fmaf(ny[s], y4.y, fmaf(nz[s], z4.y, w4.y)));
                float qc = fmaf(nx[s], x4.z, fmaf(ny[s], y4.z, fmaf(nz[s], z4.z, w4.z)));
                float qd = fmaf(nx[s], x4.w, fmaf(ny[s], y4.w, fmaf(nz[s], z4.w, w4.w)));
                INS5(q0[s], q1[s], q2[s], q3[s], q4[s], qa);
                INS5(q0[s], q1[s], q2[s], q3[s], q4[s], qb);
                INS5(q0[s], q1[s], q2[s], q3[s], q4[s], qc);
                INS5(q0[s], q1[s], q2[s], q3[s], q4[s], qd);
            }
        }
        __syncthreads();
    }

    // ---- butterfly merge across the 64 lanes ----
    // lowest-5 of two sorted-5 via r_k = min over i+j=k of max(a_i,b_j)
#pragma unroll
    for (int off = 32; off >= 1; off >>= 1) {
#pragma unroll
        for (int s = 0; s < SRC_PER_WAVE; ++s) {
            float a0 = q0[s], a1 = q1[s], a2 = q2[s], a3 = q3[s], a4 = q4[s];
            float b0 = __shfl_xor(a0, off);
            float b1 = __shfl_xor(a1, off);
            float b2 = __shfl_xor(a2, off);
            float b3 = __shfl_xor(a3, off);
            float b4 = __shfl_xor(a4, off);
            q0[s] = fminf(a0, b0);
            q1[s] = fminf(fminf(a1, b1), fmaxf(a0, b0));
            q2[s] = fminf(fminf(a2, b2), fminf(fmaxf(a0, b1), fmaxf(a1, b0)));
            q3[s] = fminf(fminf(a3, b3),
                          fminf(fmaxf(a0, b2), fminf(fmaxf(a1, b1), fmaxf(a2, b0))));
            q4[s] = fminf(fminf(a4, b4),
                          fminf(fminf(fmaxf(a0, b3), fmaxf(a1, b2)),
                                fminf(fmaxf(a2, b1), fmaxf(a3, b0))));
        }
    }

    // ---- per-wave result -> block reduce -> 2 atomics ----
    if (lane == 0) {
        float ssum = 0.0f, scnt = 0.0f;
#pragma unroll
        for (int s = 0; s < SRC_PER_WAVE; ++s) {
            float d0 = sqrtf(fmaxf(q0[s] + s2a[s], 1e-12f));
            float d1 = sqrtf(fmaxf(q1[s] + s2a[s], 1e-12f));
            float d2 = sqrtf(fmaxf(q2[s] + s2a[s], 1e-12f));
            float d3 = sqrtf(fmaxf(q3[s] + s2a[s], 1e-12f));
            float d4 = sqrtf(fmaxf(q4[s] + s2a[s], 1e-12f));
            ssum += svalid[s] * (d0 + d1 + d2 + d3 + d4);
            scnt += svalid[s];
        }
        red_s[wv] = ssum;
        red_c[wv] = scnt;
    }
    __syncthreads();

    if (tid == 0) {
        float s = 0.0f, c = 0.0f;
#pragma unroll
        for (int i = 0; i < WAVES_PER_BLOCK; ++i) {
            s += red_s[i];
            c += red_c[i];
        }
        atomicAdd(&acc[0], s);
        atomicAdd(&acc[1], c);
    }
}

// ---------------- launch ----------------

extern "C" void kernel_launch(void* const* d_in, const int* in_sizes, int n_in,
                              void* d_out, int out_size, void* d_ws, size_t ws_size,
                              hipStream_t stream) {
    const float* src = (const float*)d_in[0];
    const float* tgt = (const float*)d_in[1];
    const int ms = in_sizes[0] / 3;
    const int nt = in_sizes[1] / 3;

    float* acc = (float*)d_ws;
    init_acc_kernel<<<1, 1, 0, stream>>>(acc);

    const int blocks = (ms + SRC_PER_BLOCK - 1) / SRC_PER_BLOCK;
    knn_kernel<<<blocks, BLOCK, 0, stream>>>(src, tgt, acc, ms, nt);

    finalize_kernel<<<1, 1, 0, stream>>>(acc, (float*)d_out);
}

// Round 3
// 82.177 us; speedup vs baseline: 1.9222x; 1.3038x over previous
//
#include <hip/hip_runtime.h>
#include <math.h>

#define KNN 5
#define BLOCK 256
#define TILE_T 2048                    // targets per LDS tile (SoA, 32 KB)
#define WAVES_PER_BLOCK (BLOCK / 64)   // 4
#define SRC_PER_WAVE 4                 // source points owned by each wave
#define SRC_PER_BLOCK (WAVES_PER_BLOCK * SRC_PER_WAVE)  // 16

// ---------------- raw single-instruction min/max/med3 ----------------
// fminf/fmaxf can pick up canonicalization ops (v_max x,x) on loop-carried
// values; these are guaranteed 1 VALU instruction each.

__device__ __forceinline__ float vmin(float a, float b) {
    float r;
    asm("v_min_f32 %0, %1, %2" : "=v"(r) : "v"(a), "v"(b));
    return r;
}
__device__ __forceinline__ float vmax(float a, float b) {
    float r;
    asm("v_max_f32 %0, %1, %2" : "=v"(r) : "v"(a), "v"(b));
    return r;
}

// ---------------- small utility kernels ----------------

__global__ void init_acc_kernel(float* acc) {
    acc[0] = 0.0f;  // sum of knn distances over valid sources
    acc[1] = 0.0f;  // count of valid sources
}

__global__ void finalize_kernel(const float* acc, float* out) {
    out[0] = acc[0] / (acc[1] * (float)KNN);
}

// Online sorted top-5 insert. Identity: min(Kb, max(Ka, v)) == med3(Ka, Kb, v)
// for a sorted pair Ka<=Kb -> 4 med3 + 1 min = 5 VALU per insert.
#define INS5(K0, K1, K2, K3, K4, V)                                       \
    do {                                                                  \
        float _v = (V);                                                   \
        K4 = __builtin_amdgcn_fmed3f(K3, K4, _v);                         \
        K3 = __builtin_amdgcn_fmed3f(K2, K3, _v);                         \
        K2 = __builtin_amdgcn_fmed3f(K1, K2, _v);                         \
        K1 = __builtin_amdgcn_fmed3f(K0, K1, _v);                         \
        K0 = vmin(K0, _v);                                                \
    } while (0)

// ---------------- main kernel ----------------
// One wave owns 4 source points; all 64 lanes scan disjoint 4-target chunks
// of each LDS tile, maintaining 4 top-5 lists on q = |t|^2 - 2*s.t
// (monotone in d^2; |s|^2 added after selection). Lane-lists merged at the
// end with a min/max merge network per butterfly round.

__global__ __launch_bounds__(BLOCK) void knn_kernel(
        const float* __restrict__ src, const float* __restrict__ tgt,
        float* __restrict__ acc, int ms, int nt) {
    __shared__ __align__(16) float xs[TILE_T];
    __shared__ __align__(16) float ys[TILE_T];
    __shared__ __align__(16) float zs[TILE_T];
    __shared__ __align__(16) float w2[TILE_T];  // |t|^2 (or sentinel)
    __shared__ float red_s[WAVES_PER_BLOCK];
    __shared__ float red_c[WAVES_PER_BLOCK];

    const int tid = threadIdx.x;
    const int wv = tid >> 6;
    const int lane = tid & 63;
    const int sbase = (blockIdx.x * WAVES_PER_BLOCK + wv) * SRC_PER_WAVE;

    // source points for this wave: precompute -2*s and |s|^2
    float nx[SRC_PER_WAVE], ny[SRC_PER_WAVE], nz[SRC_PER_WAVE];
    float s2a[SRC_PER_WAVE], svalid[SRC_PER_WAVE];
#pragma unroll
    for (int s = 0; s < SRC_PER_WAVE; ++s) {
        int sp = sbase + s;
        float x = 0.0f, y = 0.0f, z = 0.0f;
        if (sp < ms) {
            x = src[3 * sp + 0];
            y = src[3 * sp + 1];
            z = src[3 * sp + 2];
        }
        svalid[s] = (sp < ms && (x != 0.0f || y != 0.0f || z != 0.0f)) ? 1.0f : 0.0f;
        nx[s] = -2.0f * x;
        ny[s] = -2.0f * y;
        nz[s] = -2.0f * z;
        s2a[s] = fmaf(x, x, fmaf(y, y, z * z));
    }

    // 4 ascending top-5 lists (on q); fully register-resident (static idx only)
    float q0[SRC_PER_WAVE], q1[SRC_PER_WAVE], q2[SRC_PER_WAVE],
          q3[SRC_PER_WAVE], q4[SRC_PER_WAVE];
#pragma unroll
    for (int s = 0; s < SRC_PER_WAVE; ++s) {
        q0[s] = 1e30f; q1[s] = 1e30f; q2[s] = 1e30f; q3[s] = 1e30f; q4[s] = 1e30f;
    }

    for (int t0 = 0; t0 < nt; t0 += TILE_T) {
        // ---- stage tile into SoA LDS, sanitizing invalid targets ----
        if (t0 + TILE_T <= nt) {
            // full tile: vectorized, 3 float4 loads unpack to 4 targets
            const float4* t4 = reinterpret_cast<const float4*>(tgt + (size_t)t0 * 3);
#pragma unroll
            for (int cc = 0; cc < TILE_T / 4; cc += BLOCK) {
                int c = cc + tid;  // 4-target chunk within tile
                float4 f0 = t4[3 * c + 0];
                float4 f1 = t4[3 * c + 1];
                float4 f2 = t4[3 * c + 2];
                float px[4] = {f0.x, f0.w, f1.z, f2.y};
                float py[4] = {f0.y, f1.x, f1.w, f2.z};
                float pz[4] = {f0.z, f1.y, f2.x, f2.w};
                float pw[4];
#pragma unroll
                for (int j = 0; j < 4; ++j) {
                    bool v = (px[j] != 0.0f) || (py[j] != 0.0f) || (pz[j] != 0.0f);
                    if (!v) { px[j] = 1e10f; py[j] = 0.0f; pz[j] = 0.0f; }
                    pw[j] = fmaf(px[j], px[j], fmaf(py[j], py[j], pz[j] * pz[j]));
                }
                int t = 4 * c;
                *reinterpret_cast<float4*>(&xs[t]) = make_float4(px[0], px[1], px[2], px[3]);
                *reinterpret_cast<float4*>(&ys[t]) = make_float4(py[0], py[1], py[2], py[3]);
                *reinterpret_cast<float4*>(&zs[t]) = make_float4(pz[0], pz[1], pz[2], pz[3]);
                *reinterpret_cast<float4*>(&w2[t]) = make_float4(pw[0], pw[1], pw[2], pw[3]);
            }
        } else {
            // partial tail tile: scalar guarded + sentinel padding
            int cnt = nt - t0;
            for (int t = tid; t < TILE_T; t += BLOCK) {
                float x = 1e10f, y = 0.0f, z = 0.0f;
                if (t < cnt) {
                    x = tgt[3 * (size_t)(t0 + t) + 0];
                    y = tgt[3 * (size_t)(t0 + t) + 1];
                    z = tgt[3 * (size_t)(t0 + t) + 2];
                    if (x == 0.0f && y == 0.0f && z == 0.0f) { x = 1e10f; y = 0.0f; z = 0.0f; }
                }
                xs[t] = x; ys[t] = y; zs[t] = z;
                w2[t] = fmaf(x, x, fmaf(y, y, z * z));
            }
        }
        __syncthreads();

        // ---- scan tile: each lane takes 4 consecutive targets per iter ----
#pragma unroll 2
        for (int i = 0; i < TILE_T / 256; ++i) {
            int t = (i << 8) + (lane << 2);
            float4 x4 = *reinterpret_cast<const float4*>(&xs[t]);
            float4 y4 = *reinterpret_cast<const float4*>(&ys[t]);
            float4 z4 = *reinterpret_cast<const float4*>(&zs[t]);
            float4 w4 = *reinterpret_cast<const float4*>(&w2[t]);
#pragma unroll
            for (int s = 0; s < SRC_PER_WAVE; ++s) {
                float qa = fmaf(nx[s], x4.x, fmaf(ny[s], y4.x, fmaf(nz[s], z4.x, w4.x)));
                float qb = fmaf(nx[s], x4.y, fmaf(ny[s], y4.y, fmaf(nz[s], z4.y, w4.y)));
                float qc = fmaf(nx[s], x4.z, fmaf(ny[s], y4.z, fmaf(nz[s], z4.z, w4.z)));
                float qd = fmaf(nx[s], x4.w, fmaf(ny[s], y4.w, fmaf(nz[s], z4.w, w4.w)));
                INS5(q0[s], q1[s], q2[s], q3[s], q4[s], qa);
                INS5(q0[s], q1[s], q2[s], q3[s], q4[s], qb);
                INS5(q0[s], q1[s], q2[s], q3[s], q4[s], qc);
                INS5(q0[s], q1[s], q2[s], q3[s], q4[s], qd);
            }
        }
        __syncthreads();
    }

    // ---- butterfly merge across the 64 lanes ----
    // lowest-5 of two sorted-5 via r_k = min over i+j=k of max(a_i,b_j)
#pragma unroll
    for (int off = 32; off >= 1; off >>= 1) {
#pragma unroll
        for (int s = 0; s < SRC_PER_WAVE; ++s) {
            float a0 = q0[s], a1 = q1[s], a2 = q2[s], a3 = q3[s], a4 = q4[s];
            float b0 = __shfl_xor(a0, off);
            float b1 = __shfl_xor(a1, off);
            float b2 = __shfl_xor(a2, off);
            float b3 = __shfl_xor(a3, off);
            float b4 = __shfl_xor(a4, off);
            q0[s] = vmin(a0, b0);
            q1[s] = vmin(vmin(a1, b1), vmax(a0, b0));
            q2[s] = vmin(vmin(a2, b2), vmin(vmax(a0, b1), vmax(a1, b0)));
            q3[s] = vmin(vmin(a3, b3),
                         vmin(vmax(a0, b2), vmin(vmax(a1, b1), vmax(a2, b0))));
            q4[s] = vmin(vmin(a4, b4),
                         vmin(vmin(vmax(a0, b3), vmax(a1, b2)),
                              vmin(vmax(a2, b1), vmax(a3, b0))));
        }
    }

    // ---- per-wave result -> block reduce -> 2 atomics ----
    if (lane == 0) {
        float ssum = 0.0f, scnt = 0.0f;
#pragma unroll
        for (int s = 0; s < SRC_PER_WAVE; ++s) {
            float d0 = sqrtf(fmaxf(q0[s] + s2a[s], 1e-12f));
            float d1 = sqrtf(fmaxf(q1[s] + s2a[s], 1e-12f));
            float d2 = sqrtf(fmaxf(q2[s] + s2a[s], 1e-12f));
            float d3 = sqrtf(fmaxf(q3[s] + s2a[s], 1e-12f));
            float d4 = sqrtf(fmaxf(q4[s] + s2a[s], 1e-12f));
            ssum += svalid[s] * (d0 + d1 + d2 + d3 + d4);
            scnt += svalid[s];
        }
        red_s[wv] = ssum;
        red_c[wv] = scnt;
    }
    __syncthreads();

    if (tid == 0) {
        float s = 0.0f, c = 0.0f;
#pragma unroll
        for (int i = 0; i < WAVES_PER_BLOCK; ++i) {
            s += red_s[i];
            c += red_c[i];
        }
        atomicAdd(&acc[0], s);
        atomicAdd(&acc[1], c);
    }
}

// ---------------- launch ----------------

extern "C" void kernel_launch(void* const* d_in, const int* in_sizes, int n_in,
                              void* d_out, int out_size, void* d_ws, size_t ws_size,
                              hipStream_t stream) {
    const float* src = (const float*)d_in[0];
    const float* tgt = (const float*)d_in[1];
    const int ms = in_sizes[0] / 3;
    const int nt = in_sizes[1] / 3;

    float* acc = (float*)d_ws;
    init_acc_kernel<<<1, 1, 0, stream>>>(acc);

    const int blocks = (ms + SRC_PER_BLOCK - 1) / SRC_PER_BLOCK;
    knn_kernel<<<blocks, BLOCK, 0, stream>>>(src, tgt, acc, ms, nt);

    finalize_kernel<<<1, 1, 0, stream>>>(acc, (float*)d_out);
}

// Round 4
// 80.276 us; speedup vs baseline: 1.9678x; 1.0237x over previous
//
#include <hip/hip_runtime.h>
#include <math.h>

#define KNN 5
#define BLOCK 256
#define TILE_T 2048                    // targets per LDS tile (SoA, 32 KB)
#define WAVES_PER_BLOCK (BLOCK / 64)   // 4
#define SRCW 8                         // source points owned by each wave
#define SRC_PER_BLOCK (WAVES_PER_BLOCK * SRCW)  // 32
#define NSPLIT 2                       // target-range halves (grid.y)

// ---------------- raw single-instruction min/max ----------------
__device__ __forceinline__ float vmin(float a, float b) {
    float r;
    asm("v_min_f32 %0, %1, %2" : "=v"(r) : "v"(a), "v"(b));
    return r;
}
__device__ __forceinline__ float vmax(float a, float b) {
    float r;
    asm("v_max_f32 %0, %1, %2" : "=v"(r) : "v"(a), "v"(b));
    return r;
}

// Online sorted top-5 insert: min(Kb,max(Ka,v)) == med3(Ka,Kb,v) for Ka<=Kb.
// 4 med3 + 1 min = 5 VALU per insert.
#define INS5(K0, K1, K2, K3, K4, V)                                       \
    do {                                                                  \
        float _v = (V);                                                   \
        K4 = __builtin_amdgcn_fmed3f(K3, K4, _v);                         \
        K3 = __builtin_amdgcn_fmed3f(K2, K3, _v);                         \
        K2 = __builtin_amdgcn_fmed3f(K1, K2, _v);                         \
        K1 = __builtin_amdgcn_fmed3f(K0, K1, _v);                         \
        K0 = vmin(K0, _v);                                                \
    } while (0)

// lowest-5 of two sorted-5 lists (a -> result in place)
#define MERGE55(a0, a1, a2, a3, a4, b0, b1, b2, b3, b4)                   \
    do {                                                                  \
        float r0 = vmin(a0, b0);                                          \
        float r1 = vmin(vmin(a1, b1), vmax(a0, b0));                      \
        float r2 = vmin(vmin(a2, b2), vmin(vmax(a0, b1), vmax(a1, b0)));  \
        float r3 = vmin(vmin(a3, b3),                                     \
                        vmin(vmax(a0, b2), vmin(vmax(a1, b1), vmax(a2, b0)))); \
        float r4 = vmin(vmin(a4, b4),                                     \
                        vmin(vmin(vmax(a0, b3), vmax(a1, b2)),            \
                             vmin(vmax(a2, b1), vmax(a3, b0))));          \
        a0 = r0; a1 = r1; a2 = r2; a3 = r3; a4 = r4;                      \
    } while (0)

// ---------------- small utility kernels ----------------

__global__ void init_acc_kernel(float* acc) {
    acc[0] = 0.0f;
    acc[1] = 0.0f;
}

__global__ void finalize_kernel(const float* acc, float* out) {
    out[0] = acc[0] / (acc[1] * (float)KNN);
}

// ---------------- main kernel (split targets) ----------------
// Each wave owns 8 source points; block scans its gridDim.y-th slice of the
// targets through 32KB SoA LDS tiles. Top-5 kept on q = |t|^2 - 2*s.t
// (monotone in d^2). Per-half sorted-5 q-lists written to `partials`
// (8 floats/record); a second kernel merges halves and reduces.

__global__ __launch_bounds__(BLOCK, 4) void knn_split_kernel(
        const float* __restrict__ src, const float* __restrict__ tgt,
        float* __restrict__ partials, int ms, int nt, int nth, int spad) {
    __shared__ __align__(16) float xs[TILE_T];
    __shared__ __align__(16) float ys[TILE_T];
    __shared__ __align__(16) float zs[TILE_T];
    __shared__ __align__(16) float w2[TILE_T];

    const int tid = threadIdx.x;
    const int wv = tid >> 6;
    const int lane = tid & 63;
    const int sbase = (blockIdx.x * WAVES_PER_BLOCK + wv) * SRCW;
    const int half = blockIdx.y;
    const int hbase = half * nth;
    const int hend = min(nt, hbase + nth);

    float nx[SRCW], ny[SRCW], nz[SRCW];
#pragma unroll
    for (int s = 0; s < SRCW; ++s) {
        int sp = sbase + s;
        float x = 0.0f, y = 0.0f, z = 0.0f;
        if (sp < ms) {
            x = src[3 * sp + 0];
            y = src[3 * sp + 1];
            z = src[3 * sp + 2];
        }
        nx[s] = -2.0f * x;
        ny[s] = -2.0f * y;
        nz[s] = -2.0f * z;
    }

    float q0[SRCW], q1[SRCW], q2[SRCW], q3[SRCW], q4[SRCW];
#pragma unroll
    for (int s = 0; s < SRCW; ++s) {
        q0[s] = 1e30f; q1[s] = 1e30f; q2[s] = 1e30f; q3[s] = 1e30f; q4[s] = 1e30f;
    }

    for (int t0 = hbase; t0 < hend; t0 += TILE_T) {
        // ---- stage tile into SoA LDS, sanitizing invalid targets ----
        if (t0 + TILE_T <= hend) {
#pragma unroll
            for (int cc = 0; cc < TILE_T / 4; cc += BLOCK) {
                int c = cc + tid;
                const float4* t4 = reinterpret_cast<const float4*>(tgt + (size_t)t0 * 3);
                float4 f0 = t4[3 * c + 0];
                float4 f1 = t4[3 * c + 1];
                float4 f2 = t4[3 * c + 2];
                float px[4] = {f0.x, f0.w, f1.z, f2.y};
                float py[4] = {f0.y, f1.x, f1.w, f2.z};
                float pz[4] = {f0.z, f1.y, f2.x, f2.w};
                float pw[4];
#pragma unroll
                for (int j = 0; j < 4; ++j) {
                    bool v = (px[j] != 0.0f) || (py[j] != 0.0f) || (pz[j] != 0.0f);
                    if (!v) { px[j] = 1e10f; py[j] = 0.0f; pz[j] = 0.0f; }
                    pw[j] = fmaf(px[j], px[j], fmaf(py[j], py[j], pz[j] * pz[j]));
                }
                int t = 4 * c;
                *reinterpret_cast<float4*>(&xs[t]) = make_float4(px[0], px[1], px[2], px[3]);
                *reinterpret_cast<float4*>(&ys[t]) = make_float4(py[0], py[1], py[2], py[3]);
                *reinterpret_cast<float4*>(&zs[t]) = make_float4(pz[0], pz[1], pz[2], pz[3]);
                *reinterpret_cast<float4*>(&w2[t]) = make_float4(pw[0], pw[1], pw[2], pw[3]);
            }
        } else {
            int cnt = hend - t0;
            for (int t = tid; t < TILE_T; t += BLOCK) {
                float x = 1e10f, y = 0.0f, z = 0.0f;
                if (t < cnt) {
                    x = tgt[3 * (size_t)(t0 + t) + 0];
                    y = tgt[3 * (size_t)(t0 + t) + 1];
                    z = tgt[3 * (size_t)(t0 + t) + 2];
                    if (x == 0.0f && y == 0.0f && z == 0.0f) { x = 1e10f; y = 0.0f; z = 0.0f; }
                }
                xs[t] = x; ys[t] = y; zs[t] = z;
                w2[t] = fmaf(x, x, fmaf(y, y, z * z));
            }
        }
        __syncthreads();

        // ---- scan tile: each lane takes 4 consecutive targets per iter ----
#pragma unroll 2
        for (int i = 0; i < TILE_T / 256; ++i) {
            int t = (i << 8) + (lane << 2);
            float4 x4 = *reinterpret_cast<const float4*>(&xs[t]);
            float4 y4 = *reinterpret_cast<const float4*>(&ys[t]);
            float4 z4 = *reinterpret_cast<const float4*>(&zs[t]);
            float4 w4 = *reinterpret_cast<const float4*>(&w2[t]);
#pragma unroll
            for (int s = 0; s < SRCW; ++s) {
                float qa = fmaf(nx[s], x4.x, fmaf(ny[s], y4.x, fmaf(nz[s], z4.x, w4.x)));
                float qb = fmaf(nx[s], x4.y, fmaf(ny[s], y4.y, fmaf(nz[s], z4.y, w4.y)));
                float qc = fmaf(nx[s], x4.z, fmaf(ny[s], y4.z, fmaf(nz[s], z4.z, w4.z)));
                float qd = fmaf(nx[s], x4.w, fmaf(ny[s], y4.w, fmaf(nz[s], z4.w, w4.w)));
                INS5(q0[s], q1[s], q2[s], q3[s], q4[s], qa);
                INS5(q0[s], q1[s], q2[s], q3[s], q4[s], qb);
                INS5(q0[s], q1[s], q2[s], q3[s], q4[s], qc);
                INS5(q0[s], q1[s], q2[s], q3[s], q4[s], qd);
            }
        }
        __syncthreads();
    }

    // ---- butterfly merge across 64 lanes (all lanes end with the result) ----
#pragma unroll
    for (int off = 32; off >= 1; off >>= 1) {
#pragma unroll
        for (int s = 0; s < SRCW; ++s) {
            float b0 = __shfl_xor(q0[s], off);
            float b1 = __shfl_xor(q1[s], off);
            float b2 = __shfl_xor(q2[s], off);
            float b3 = __shfl_xor(q3[s], off);
            float b4 = __shfl_xor(q4[s], off);
            MERGE55(q0[s], q1[s], q2[s], q3[s], q4[s], b0, b1, b2, b3, b4);
        }
    }

    // ---- write per-half sorted q-lists (8 floats per record) ----
    if (lane == 0) {
        float* base = partials + ((size_t)half * spad + sbase) * 8;
#pragma unroll
        for (int s = 0; s < SRCW; ++s) {
            if (sbase + s < ms) {
                *reinterpret_cast<float4*>(base + 8 * s) =
                    make_float4(q0[s], q1[s], q2[s], q3[s]);
                *reinterpret_cast<float4*>(base + 8 * s + 4) =
                    make_float4(q4[s], 0.0f, 0.0f, 0.0f);
            }
        }
    }
}

// ---------------- merge halves + reduce ----------------

__global__ __launch_bounds__(BLOCK) void merge_kernel(
        const float* __restrict__ src, const float* __restrict__ partials,
        float* __restrict__ acc, int ms, int spad) {
    __shared__ float red_s[WAVES_PER_BLOCK];
    __shared__ float red_c[WAVES_PER_BLOCK];

    const int tid = threadIdx.x;
    const int sp = blockIdx.x * BLOCK + tid;

    float ssum = 0.0f, scnt = 0.0f;
    if (sp < ms) {
        const float* r0p = partials + (size_t)sp * 8;
        const float* r1p = partials + ((size_t)spad + sp) * 8;
        float4 lo0 = *reinterpret_cast<const float4*>(r0p);
        float a4 = r0p[4];
        float4 lo1 = *reinterpret_cast<const float4*>(r1p);
        float b4 = r1p[4];
        float a0 = lo0.x, a1 = lo0.y, a2 = lo0.z, a3 = lo0.w;
        MERGE55(a0, a1, a2, a3, a4, lo1.x, lo1.y, lo1.z, lo1.w, b4);

        float x = src[3 * sp + 0];
        float y = src[3 * sp + 1];
        float z = src[3 * sp + 2];
        bool valid = (x != 0.0f) || (y != 0.0f) || (z != 0.0f);
        float s2 = fmaf(x, x, fmaf(y, y, z * z));
        if (valid) {
            ssum = sqrtf(fmaxf(a0 + s2, 1e-12f)) + sqrtf(fmaxf(a1 + s2, 1e-12f)) +
                   sqrtf(fmaxf(a2 + s2, 1e-12f)) + sqrtf(fmaxf(a3 + s2, 1e-12f)) +
                   sqrtf(fmaxf(a4 + s2, 1e-12f));
            scnt = 1.0f;
        }
    }

    // wave reduce then block reduce
#pragma unroll
    for (int off = 32; off >= 1; off >>= 1) {
        ssum += __shfl_down(ssum, off);
        scnt += __shfl_down(scnt, off);
    }
    if ((tid & 63) == 0) {
        red_s[tid >> 6] = ssum;
        red_c[tid >> 6] = scnt;
    }
    __syncthreads();
    if (tid == 0) {
        float s = 0.0f, c = 0.0f;
#pragma unroll
        for (int i = 0; i < WAVES_PER_BLOCK; ++i) { s += red_s[i]; c += red_c[i]; }
        atomicAdd(&acc[0], s);
        atomicAdd(&acc[1], c);
    }
}

// ---------------- fallback monolithic kernel (round-3, 4 src/wave) ----------------

__global__ __launch_bounds__(BLOCK) void knn_mono_kernel(
        const float* __restrict__ src, const float* __restrict__ tgt,
        float* __restrict__ acc, int ms, int nt) {
    __shared__ __align__(16) float xs[TILE_T];
    __shared__ __align__(16) float ys[TILE_T];
    __shared__ __align__(16) float zs[TILE_T];
    __shared__ __align__(16) float w2[TILE_T];
    __shared__ float red_s[WAVES_PER_BLOCK];
    __shared__ float red_c[WAVES_PER_BLOCK];

    const int tid = threadIdx.x;
    const int wv = tid >> 6;
    const int lane = tid & 63;
    const int sbase = (blockIdx.x * WAVES_PER_BLOCK + wv) * 4;

    float nx[4], ny[4], nz[4], s2a[4], svalid[4];
#pragma unroll
    for (int s = 0; s < 4; ++s) {
        int sp = sbase + s;
        float x = 0.0f, y = 0.0f, z = 0.0f;
        if (sp < ms) {
            x = src[3 * sp + 0]; y = src[3 * sp + 1]; z = src[3 * sp + 2];
        }
        svalid[s] = (sp < ms && (x != 0.0f || y != 0.0f || z != 0.0f)) ? 1.0f : 0.0f;
        nx[s] = -2.0f * x; ny[s] = -2.0f * y; nz[s] = -2.0f * z;
        s2a[s] = fmaf(x, x, fmaf(y, y, z * z));
    }
    float q0[4], q1[4], q2[4], q3[4], q4[4];
#pragma unroll
    for (int s = 0; s < 4; ++s) {
        q0[s] = 1e30f; q1[s] = 1e30f; q2[s] = 1e30f; q3[s] = 1e30f; q4[s] = 1e30f;
    }
    for (int t0 = 0; t0 < nt; t0 += TILE_T) {
        int cnt = min(TILE_T, nt - t0);
        for (int t = tid; t < TILE_T; t += BLOCK) {
            float x = 1e10f, y = 0.0f, z = 0.0f;
            if (t < cnt) {
                x = tgt[3 * (size_t)(t0 + t) + 0];
                y = tgt[3 * (size_t)(t0 + t) + 1];
                z = tgt[3 * (size_t)(t0 + t) + 2];
                if (x == 0.0f && y == 0.0f && z == 0.0f) { x = 1e10f; y = 0.0f; z = 0.0f; }
            }
            xs[t] = x; ys[t] = y; zs[t] = z;
            w2[t] = fmaf(x, x, fmaf(y, y, z * z));
        }
        __syncthreads();
#pragma unroll 2
        for (int i = 0; i < TILE_T / 256; ++i) {
            int t = (i << 8) + (lane << 2);
            float4 x4 = *reinterpret_cast<const float4*>(&xs[t]);
            float4 y4 = *reinterpret_cast<const float4*>(&ys[t]);
            float4 z4 = *reinterpret_cast<const float4*>(&zs[t]);
            float4 w4 = *reinterpret_cast<const float4*>(&w2[t]);
#pragma unroll
            for (int s = 0; s < 4; ++s) {
                float qa = fmaf(nx[s], x4.x, fmaf(ny[s], y4.x, fmaf(nz[s], z4.x, w4.x)));
                float qb = fmaf(nx[s], x4.y, fmaf(ny[s], y4.y, fmaf(nz[s], z4.y, w4.y)));
                float qc = fmaf(nx[s], x4.z, fmaf(ny[s], y4.z, fmaf(nz[s], z4.z, w4.z)));
                float qd = fmaf(nx[s], x4.w, fmaf(ny[s], y4.w, fmaf(nz[s], z4.w, w4.w)));
                INS5(q0[s], q1[s], q2[s], q3[s], q4[s], qa);
                INS5(q0[s], q1[s], q2[s], q3[s], q4[s], qb);
                INS5(q0[s], q1[s], q2[s], q3[s], q4[s], qc);
                INS5(q0[s], q1[s], q2[s], q3[s], q4[s], qd);
            }
        }
        __syncthreads();
    }
#pragma unroll
    for (int off = 32; off >= 1; off >>= 1) {
#pragma unroll
        for (int s = 0; s < 4; ++s) {
            float b0 = __shfl_xor(q0[s], off);
            float b1 = __shfl_xor(q1[s], off);
            float b2 = __shfl_xor(q2[s], off);
            float b3 = __shfl_xor(q3[s], off);
            float b4 = __shfl_xor(q4[s], off);
            MERGE55(q0[s], q1[s], q2[s], q3[s], q4[s], b0, b1, b2, b3, b4);
        }
    }
    if (lane == 0) {
        float ssum = 0.0f, scnt = 0.0f;
#pragma unroll
        for (int s = 0; s < 4; ++s) {
            float d0 = sqrtf(fmaxf(q0[s] + s2a[s], 1e-12f));
            float d1 = sqrtf(fmaxf(q1[s] + s2a[s], 1e-12f));
            float d2 = sqrtf(fmaxf(q2[s] + s2a[s], 1e-12f));
            float d3 = sqrtf(fmaxf(q3[s] + s2a[s], 1e-12f));
            float d4 = sqrtf(fmaxf(q4[s] + s2a[s], 1e-12f));
            ssum += svalid[s] * (d0 + d1 + d2 + d3 + d4);
            scnt += svalid[s];
        }
        red_s[wv] = ssum;
        red_c[wv] = scnt;
    }
    __syncthreads();
    if (tid == 0) {
        float s = 0.0f, c = 0.0f;
#pragma unroll
        for (int i = 0; i < WAVES_PER_BLOCK; ++i) { s += red_s[i]; c += red_c[i]; }
        atomicAdd(&acc[0], s);
        atomicAdd(&acc[1], c);
    }
}

// ---------------- launch ----------------

extern "C" void kernel_launch(void* const* d_in, const int* in_sizes, int n_in,
                              void* d_out, int out_size, void* d_ws, size_t ws_size,
                              hipStream_t stream) {
    const float* src = (const float*)d_in[0];
    const float* tgt = (const float*)d_in[1];
    const int ms = in_sizes[0] / 3;
    const int nt = in_sizes[1] / 3;

    float* acc = (float*)d_ws;
    init_acc_kernel<<<1, 1, 0, stream>>>(acc);

    const int ngroups = (ms + SRC_PER_BLOCK - 1) / SRC_PER_BLOCK;
    const int spad = ngroups * SRC_PER_BLOCK;
    // targets per half, rounded up to a whole tile
    int nth = (nt + NSPLIT - 1) / NSPLIT;
    nth = (nth + TILE_T - 1) / TILE_T * TILE_T;

    const size_t need = 16 + (size_t)NSPLIT * spad * 8 * sizeof(float);

    if (ws_size >= need) {
        float* partials = (float*)((char*)d_ws + 16);
        dim3 grid(ngroups, NSPLIT);
        knn_split_kernel<<<grid, BLOCK, 0, stream>>>(src, tgt, partials, ms, nt, nth, spad);
        merge_kernel<<<(ms + BLOCK - 1) / BLOCK, BLOCK, 0, stream>>>(src, partials, acc, ms, spad);
    } else {
        const int blocks = (ms + 15) / 16;
        knn_mono_kernel<<<blocks, BLOCK, 0, stream>>>(src, tgt, acc, ms, nt);
    }

    finalize_kernel<<<1, 1, 0, stream>>>(acc, (float*)d_out);
}